// Round 3
// baseline (55.670 us; speedup 1.0000x reference)
//
#include <hip/hip_runtime.h>

// 3x3 VALID correlation on 4096x4096 fp32 -> 4094x4094 fp32, + bias.
// out[r][c] = sum_{kh,kw} X[r+kh][c+kw] * W[kh][kw] + bias (no kernel flip).
//
// Register tiling: each thread computes R=4 output rows x C=8 output cols.
// Loads 6 input rows x 12 floats (3x float4), one row live at a time.
// Edges handled by clamping load addresses: clamped (garbage) values only
// ever flow into accumulators whose output row/col is >= 4094, which are
// masked at store time.

constexpr int Hin = 4096;
constexpr int Win = 4096;
constexpr int OH  = 4094;
constexpr int OW  = 4094;

constexpr int C = 8;    // cols per thread
constexpr int R = 4;    // rows per thread
constexpr int CT = 512; // threads per row-strip: 512*8 = 4096 cols
constexpr int RT = 1024;// row strips: 1024*4 = 4096 rows (covers 4094)

typedef float f32x2 __attribute__((ext_vector_type(2)));

__global__ __launch_bounds__(256) void conv3x3_kernel(
    const float* __restrict__ X, const float* __restrict__ Wt,
    const float* __restrict__ B, float* __restrict__ Out)
{
    // XCD-chunked block swizzle (gridDim.x = 2048, divisible by 8):
    // vertically adjacent row strips land on the same XCD L2.
    int nb = gridDim.x;
    int b  = blockIdx.x;
    int b2 = (b & 7) * (nb >> 3) + (b >> 3);

    int t   = b2 * 256 + threadIdx.x;
    int cid = t & (CT - 1);
    int rid = t >> 9;          // t / CT
    int c0  = cid * C;         // multiple of 8 -> all quad indices mult of 4
    int r0  = rid * R;

    float w[9];
#pragma unroll
    for (int i = 0; i < 9; ++i) w[i] = Wt[i];
    const float bias = B[0];

    float acc[R][C];
#pragma unroll
    for (int i = 0; i < R; ++i)
#pragma unroll
        for (int j = 0; j < C; ++j) acc[i][j] = bias;

    // Third quad would read floats [c0+8 .. c0+11]; clamp so the rightmost
    // strip (c0=4088) reads in-bounds garbage that only feeds masked cols.
    int q2off = (c0 + 8 <= Win - 4) ? (c0 + 8) : (Win - 4);

#pragma unroll
    for (int ir = 0; ir < R + 2; ++ir) {
        int rr = r0 + ir;
        if (rr > Hin - 1) rr = Hin - 1;   // clamp: feeds only masked rows
        const float* row = X + (size_t)rr * Win;
        float4 q0 = *reinterpret_cast<const float4*>(row + c0);
        float4 q1 = *reinterpret_cast<const float4*>(row + c0 + 4);
        float4 q2 = *reinterpret_cast<const float4*>(row + q2off);
        float v[12] = {q0.x, q0.y, q0.z, q0.w,
                       q1.x, q1.y, q1.z, q1.w,
                       q2.x, q2.y, q2.z, q2.w};
#pragma unroll
        for (int kh = 0; kh < 3; ++kh) {
            int orr = ir - kh;            // which of my output rows this feeds
            if (orr >= 0 && orr < R) {
#pragma unroll
                for (int kw = 0; kw < 3; ++kw) {
                    float wv = w[kh * 3 + kw];
#pragma unroll
                    for (int j = 0; j < C; ++j)
                        acc[orr][j] = fmaf(v[j + kw], wv, acc[orr][j]);
                }
            }
        }
    }

#pragma unroll
    for (int i = 0; i < R; ++i) {
        int orow = r0 + i;
        if (orow < OH) {
            size_t o = (size_t)orow * OW + c0;   // even -> 8B aligned
#pragma unroll
            for (int p = 0; p < C / 2; ++p) {
                int col = c0 + 2 * p;
                if (col < OW) {                  // pairs never straddle edge
                    f32x2 val;
                    val.x = acc[i][2 * p];
                    val.y = acc[i][2 * p + 1];
                    __builtin_nontemporal_store(val,
                        reinterpret_cast<f32x2*>(Out + o + 2 * p));
                }
            }
        }
    }
}

extern "C" void kernel_launch(void* const* d_in, const int* in_sizes, int n_in,
                              void* d_out, int out_size, void* d_ws, size_t ws_size,
                              hipStream_t stream) {
    const float* X  = (const float*)d_in[0];
    const float* Wt = (const float*)d_in[1];
    const float* B  = (const float*)d_in[2];
    float* Out      = (float*)d_out;

    int total_threads = CT * RT;            // 524288
    int blocks = total_threads / 256;       // 2048 (divisible by 8)
    conv3x3_kernel<<<blocks, 256, 0, stream>>>(X, Wt, B, Out);
}

// Round 4
// 30.049 us; speedup vs baseline: 1.8527x; 1.8527x over previous
//
#include <hip/hip_runtime.h>

// 3x3 VALID correlation on 4096x4096 fp32 -> 4094x4094 fp32, + bias.
// out[r][c] = sum_{kh,kw} X[r+kh][c+kw] * W[kh][kw] + bias (no kernel flip).
//
// Register tiling: each thread computes R=4 output rows x C=8 output cols.
// ALL 6 input rows x 3 float4 quads are loaded up front (18 outstanding
// dwordx4 per lane) to maximize memory-level parallelism — round-3 counters
// showed latency-bound behavior (VALUBusy 5%, BW 3.1 TB/s << 6.3 ceiling).
// Plain (cached) float2 stores: nontemporal stores caused 2.1x write
// amplification (WRITE_SIZE 137 MB vs 64 MB output).
//
// Edges handled by clamping load addresses: clamped (garbage) values only
// flow into accumulators whose output row/col is >= 4094, masked at store.

constexpr int Hin = 4096;
constexpr int Win = 4096;
constexpr int OH  = 4094;
constexpr int OW  = 4094;

constexpr int C = 8;    // cols per thread
constexpr int R = 4;    // rows per thread
constexpr int CT = 512; // threads per row-strip: 512*8 = 4096 cols
constexpr int RT = 1024;// row strips: 1024*4 = 4096 rows (covers 4094)

__global__ __launch_bounds__(256, 4) void conv3x3_kernel(
    const float* __restrict__ X, const float* __restrict__ Wt,
    const float* __restrict__ B, float* __restrict__ Out)
{
    // XCD-chunked block swizzle (gridDim.x = 2048, divisible by 8):
    // vertically adjacent row strips land on the same XCD L2.
    int nb = gridDim.x;
    int b  = blockIdx.x;
    int b2 = (b & 7) * (nb >> 3) + (b >> 3);

    int t   = b2 * 256 + threadIdx.x;
    int cid = t & (CT - 1);
    int rid = t >> 9;          // t / CT
    int c0  = cid * C;         // multiple of 8
    int r0  = rid * R;

    // Third quad reads floats [c0+8 .. c0+11]; clamp for the rightmost strip.
    int q2off = (c0 + 8 <= Win - 4) ? (c0 + 8) : (Win - 4);

    // ---- Issue all 18 loads first: max MLP ----
    float4 q[6][3];
#pragma unroll
    for (int ir = 0; ir < 6; ++ir) {
        int rr = r0 + ir;
        if (rr > Hin - 1) rr = Hin - 1;   // clamp: feeds only masked rows
        const float* row = X + (size_t)rr * Win;
        q[ir][0] = *reinterpret_cast<const float4*>(row + c0);
        q[ir][1] = *reinterpret_cast<const float4*>(row + c0 + 4);
        q[ir][2] = *reinterpret_cast<const float4*>(row + q2off);
    }

    float w[9];
#pragma unroll
    for (int i = 0; i < 9; ++i) w[i] = Wt[i];
    const float bias = B[0];

    float acc[R][C];
#pragma unroll
    for (int i = 0; i < R; ++i)
#pragma unroll
        for (int j = 0; j < C; ++j) acc[i][j] = bias;

#pragma unroll
    for (int ir = 0; ir < 6; ++ir) {
        float v[12] = {q[ir][0].x, q[ir][0].y, q[ir][0].z, q[ir][0].w,
                       q[ir][1].x, q[ir][1].y, q[ir][1].z, q[ir][1].w,
                       q[ir][2].x, q[ir][2].y, q[ir][2].z, q[ir][2].w};
#pragma unroll
        for (int kh = 0; kh < 3; ++kh) {
            int orr = ir - kh;            // which of my output rows this feeds
            if (orr >= 0 && orr < R) {
#pragma unroll
                for (int kw = 0; kw < 3; ++kw) {
                    float wv = w[kh * 3 + kw];
#pragma unroll
                    for (int j = 0; j < C; ++j)
                        acc[orr][j] = fmaf(v[j + kw], wv, acc[orr][j]);
                }
            }
        }
    }

#pragma unroll
    for (int i = 0; i < R; ++i) {
        int orow = r0 + i;
        if (orow < OH) {
            size_t o = (size_t)orow * OW + c0;   // even -> 8B aligned
#pragma unroll
            for (int p = 0; p < C / 2; ++p) {
                int col = c0 + 2 * p;
                if (col < OW) {                  // pairs never straddle edge
                    *reinterpret_cast<float2*>(Out + o + 2 * p) =
                        make_float2(acc[i][2 * p], acc[i][2 * p + 1]);
                }
            }
        }
    }
}

extern "C" void kernel_launch(void* const* d_in, const int* in_sizes, int n_in,
                              void* d_out, int out_size, void* d_ws, size_t ws_size,
                              hipStream_t stream) {
    const float* X  = (const float*)d_in[0];
    const float* Wt = (const float*)d_in[1];
    const float* B  = (const float*)d_in[2];
    float* Out      = (float*)d_out;

    int total_threads = CT * RT;            // 524288
    int blocks = total_threads / 256;       // 2048 (divisible by 8)
    conv3x3_kernel<<<blocks, 256, 0, stream>>>(X, Wt, B, Out);
}

// Round 5
// 26.318 us; speedup vs baseline: 2.1153x; 1.1418x over previous
//
#include <hip/hip_runtime.h>

// 3x3 VALID correlation on 4096x4096 fp32 -> 4094x4094 fp32, + bias.
// out[r][c] = sum_{kh,kw} X[r+kh][c+kw] * W[kh][kw] + bias (no kernel flip).
//
// Fully-coalesced SoA layout: lane owns 2 adjacent cols (c = seg + 2*lane),
// wave owns a contiguous 128-col segment, thread computes R=8 rows.
// Per input row each lane loads two float2's (windows [c,c+2) and [c+2,c+4))
// -> every load instruction is a contiguous 512B wave access. Stores are
// perfectly coalesced float2. All 20 loads issued up front for MLP.
// Edge handling by clamping addresses; garbage only feeds masked outputs.

constexpr int Hin = 4096;
constexpr int Win = 4096;
constexpr int OH  = 4094;
constexpr int OW  = 4094;

constexpr int R = 8;          // output rows per thread
// block = 256 threads = 4 waves; wave covers 128 cols; block = 512 cols x 8 rows
// grid: 8 col-blocks x 512 row-blocks = 4096 blocks

__global__ __launch_bounds__(256, 4) void conv3x3_kernel(
    const float* __restrict__ X, const float* __restrict__ Wt,
    const float* __restrict__ B, float* __restrict__ Out)
{
    // XCD-chunked swizzle: 4096 blocks, 8 XCDs -> each XCD gets one full
    // 512-col vertical strip (consecutive row-blocks -> same XCD L2).
    int nb = gridDim.x;
    int b  = blockIdx.x;
    int b2 = (b & 7) * (nb >> 3) + (b >> 3);

    int bx   = b2 >> 9;                 // 0..7   col strip
    int by   = b2 & 511;                // 0..511 row block
    int wave = threadIdx.x >> 6;
    int lane = threadIdx.x & 63;

    int c  = bx * 512 + wave * 128 + 2 * lane;  // out col base (even)
    int r0 = by * R;

    // second window [c+2, c+4); clamp for the very last lane (c = 4094)
    int v1c = (c + 2 <= Win - 2) ? (c + 2) : (Win - 2);

    // ---- preload all input rows: 20 outstanding coalesced float2 loads ----
    float2 v0[R + 2], v1[R + 2];
#pragma unroll
    for (int ir = 0; ir < R + 2; ++ir) {
        int rr = r0 + ir;
        if (rr > Hin - 1) rr = Hin - 1;         // feeds only masked rows
        const float* row = X + (size_t)rr * Win;
        v0[ir] = *reinterpret_cast<const float2*>(row + c);
        v1[ir] = *reinterpret_cast<const float2*>(row + v1c);
    }

    float w[9];
#pragma unroll
    for (int i = 0; i < 9; ++i) w[i] = Wt[i];
    const float bias = B[0];

    float2 acc[R];
#pragma unroll
    for (int i = 0; i < R; ++i) { acc[i].x = bias; acc[i].y = bias; }

#pragma unroll
    for (int i = 0; i < R; ++i) {
#pragma unroll
        for (int kh = 0; kh < 3; ++kh) {
            int ir = i + kh;
            float w0 = w[kh * 3 + 0], w1 = w[kh * 3 + 1], w2 = w[kh * 3 + 2];
            acc[i].x = fmaf(v0[ir].x, w0, acc[i].x);
            acc[i].x = fmaf(v0[ir].y, w1, acc[i].x);
            acc[i].x = fmaf(v1[ir].x, w2, acc[i].x);
            acc[i].y = fmaf(v0[ir].y, w0, acc[i].y);
            acc[i].y = fmaf(v1[ir].x, w1, acc[i].y);
            acc[i].y = fmaf(v1[ir].y, w2, acc[i].y);
        }
    }

    // ---- perfectly coalesced float2 stores (8B aligned: c even) ----
    if (c < OW) {                                // masks only c = 4094 lane
#pragma unroll
        for (int i = 0; i < R; ++i) {
            int orow = r0 + i;
            if (orow < OH) {
                *reinterpret_cast<float2*>(Out + (size_t)orow * OW + c) = acc[i];
            }
        }
    }
}

extern "C" void kernel_launch(void* const* d_in, const int* in_sizes, int n_in,
                              void* d_out, int out_size, void* d_ws, size_t ws_size,
                              hipStream_t stream) {
    const float* X  = (const float*)d_in[0];
    const float* Wt = (const float*)d_in[1];
    const float* B  = (const float*)d_in[2];
    float* Out      = (float*)d_out;

    int blocks = 8 * 512;   // 4096, divisible by 8
    conv3x3_kernel<<<blocks, 256, 0, stream>>>(X, Wt, B, Out);
}